// Round 2
// baseline (452.738 us; speedup 1.0000x reference)
//
#include <hip/hip_runtime.h>
#include <math.h>
#include <stdint.h>

// ---------------------------------------------------------------------------
// MalaAttention on MI355X (gfx950). Round 7:
//  - gemm_qkvg ported to the 256x256 8-phase template (T2 st_16x32 LDS
//    swizzle + T3/T4 counted-vmcnt phases + T5 setprio). 512 thr, 8 waves
//    (2Mx4N), BK=64, 128KB LDS double-buffer, vmcnt(2) at K-tile bounds.
//  - RoPE epilogue kept (two 128-row half-passes through LDS T[128][264]).
//  - all other kernels unchanged from the 446us baseline.
//
// Workspace layout (bytes):
//   Xb    @ 0          32MB  bf16 X        (dead after proj -> kvp)
//   kvp   @ 0          32MB  f32 [16][bh][128][128] kv partials
//   Wcat  @ 33554432    8MB  bf16 [Wq;Wk;Wv;Wg]
//   Wob   @ 41943040    2MB  bf16 Wo
//   tab   @ 44040192    2MB  float2 [4096][64] rope sin/cos (dead after proj)
//   ksump @ 44040192  256KB  f32 [16][bh][128]   (aliases tab)
//   vsump @ 44302336  256KB  f32 [16][bh][128]
//   QKVG  @ 46137344  128MB  bf16 [16384][4096] col blocks: q|k|v|g
//   ksum  @ 180355072  16KB  f32 [bh][128]
//   vsum  @ 180371456  16KB  f32 [bh][128]
//   kvT   @ 180387840   1MB  bf16 kvT[bh][e][d]
//   obuf  @ 181960704  32MB  bf16 gated out
// ---------------------------------------------------------------------------

typedef __bf16 bf16;
typedef __bf16 bf16x2 __attribute__((ext_vector_type(2)));
typedef __bf16 bf16x4 __attribute__((ext_vector_type(4)));
typedef __bf16 bf16x8 __attribute__((ext_vector_type(8)));
typedef float f32x4 __attribute__((ext_vector_type(4)));

static constexpr float kScale = 0.08838834764831845f; // 1/sqrt(128)

__device__ __forceinline__ void async_copy16(const void* g, void* l) {
  __builtin_amdgcn_global_load_lds(
      (const __attribute__((address_space(1))) void*)(uintptr_t)g,
      (__attribute__((address_space(3))) void*)(uintptr_t)l, 16, 0, 0);
}

// ---------------------------------------------------------------------------
// Proj GEMM: QKVG = Xb @ Wcat^T. 256x256 tile, BK=64, 8-phase schedule.
// Grid 1024 (64 m-tiles x 16 n-tiles), XCD-swizzled. RoPE fused (by<8).
// ---------------------------------------------------------------------------
__global__ __launch_bounds__(512, 1) void gemm_qkvg(
    const bf16* __restrict__ A, const bf16* __restrict__ Bw,
    bf16* __restrict__ C, const float2* __restrict__ tab)
{
  // LDS: buf b at b*65536; within buf: A-half h at h*16384, B-half h at
  // 32768 + h*16384. Each half-tile: [128 rows][64 k] bf16 = 16KB, stored
  // LINEARLY (global_load_lds) with pre-swizzled global source; reads apply
  // byte ^= ((byte>>9)&1)<<5  (st_16x32: row bit2 -> byte bit5).
  __shared__ __align__(16) char smem[131072];

  const int t = threadIdx.x;
  const int bid = blockIdx.x;
  const int swz = (bid & 7) * 128 + (bid >> 3);   // XCD-contiguous chunks
  const int bx = swz & 63;                        // m tile 0..63
  const int by = swz >> 6;                        // n tile 0..15
  const long m0 = (long)bx * 256;
  const long n0 = (long)by * 256;

  // ---- staging addressing (pre-swizzled global source, linear LDS dest)
  const int d0 = t * 16;                          // dest byte in half-tile
  const int dd = d0 ^ (((d0 >> 9) & 1) << 5);     // logical byte offset
  const int rT = dd >> 7;                         // logical row 0..63
  const int cT = (dd & 127) >> 1;                 // element col (16B aligned)
  const bf16* aSt = A  + (m0 + rT) * 1024 + cT;
  const bf16* bSt = Bw + (n0 + rT) * 1024 + cT;
  char* ldsDst = smem + d0;

  // ---- fragment read addressing (swizzled)
  const int lane = t & 63, wid = t >> 6;
  const int wm = wid >> 2, wn = wid & 3;          // 2Mx4N waves
  const int fm = lane & 15, fq = lane >> 4;
  const int xsw = (fm & 4) << 3;                  // lane-constant bit5 flip
  const char* ldsA = smem + wm * 16384 + fm * 128 + (fq * 16 ^ xsw);
  const char* ldsB = smem + 32768 + (wn >> 1) * 16384 +
                     ((wn & 1) * 64 + fm) * 128 + (fq * 16 ^ xsw);

  f32x4 acc[8][4] = {};
  bf16x8 a4[4][2], b2[2][2];

#define STAGE_A(kt, h) do {                                                  \
    const bf16* s_ = aSt + (long)(h) * 131072 + (kt) * 64;                   \
    char* d_ = ldsDst + ((kt) & 1) * 65536 + (h) * 16384;                    \
    async_copy16(s_, d_);                                                    \
    async_copy16(s_ + 65536, d_ + 8192);                                     \
  } while (0)
#define STAGE_B(kt, h) do {                                                  \
    const bf16* s_ = bSt + (long)(h) * 131072 + (kt) * 64;                   \
    char* d_ = ldsDst + ((kt) & 1) * 65536 + 32768 + (h) * 16384;            \
    async_copy16(s_, d_);                                                    \
    async_copy16(s_ + 65536, d_ + 8192);                                     \
  } while (0)
#define LOAD_A(buf, qi) do {                                                 \
    const char* p_ = ldsA + (buf) * 65536 + (qi) * 8192;                     \
    a4[0][0] = *(const bf16x8*)(p_);                                         \
    a4[0][1] = *(const bf16x8*)(p_ + 64);                                    \
    a4[1][0] = *(const bf16x8*)(p_ + 2048);                                  \
    a4[1][1] = *(const bf16x8*)(p_ + 2048 + 64);                             \
    a4[2][0] = *(const bf16x8*)(p_ + 4096);                                  \
    a4[2][1] = *(const bf16x8*)(p_ + 4096 + 64);                             \
    a4[3][0] = *(const bf16x8*)(p_ + 6144);                                  \
    a4[3][1] = *(const bf16x8*)(p_ + 6144 + 64);                             \
  } while (0)
#define LOAD_B(buf, qj) do {                                                 \
    const char* p_ = ldsB + (buf) * 65536 + (qj) * 4096;                     \
    b2[0][0] = *(const bf16x8*)(p_);                                         \
    b2[0][1] = *(const bf16x8*)(p_ + 64);                                    \
    b2[1][0] = *(const bf16x8*)(p_ + 2048);                                  \
    b2[1][1] = *(const bf16x8*)(p_ + 2048 + 64);                             \
  } while (0)
#define MM1(i, j, ks)                                                        \
    acc[i][j] = __builtin_amdgcn_mfma_f32_16x16x32_bf16(                     \
        a4[(i) & 3][ks], b2[(j) & 1][ks], acc[i][j], 0, 0, 0)
#define MFMA_Q(qi, qj) do {                                                  \
    MM1(4*(qi)+0, 2*(qj)+0, 0); MM1(4*(qi)+1, 2*(qj)+0, 0);                  \
    MM1(4*(qi)+2, 2*(qj)+0, 0); MM1(4*(qi)+3, 2*(qj)+0, 0);                  \
    MM1(4*(qi)+0, 2*(qj)+1, 0); MM1(4*(qi)+1, 2*(qj)+1, 0);                  \
    MM1(4*(qi)+2, 2*(qj)+1, 0); MM1(4*(qi)+3, 2*(qj)+1, 0);                  \
    MM1(4*(qi)+0, 2*(qj)+0, 1); MM1(4*(qi)+1, 2*(qj)+0, 1);                  \
    MM1(4*(qi)+2, 2*(qj)+0, 1); MM1(4*(qi)+3, 2*(qj)+0, 1);                  \
    MM1(4*(qi)+0, 2*(qj)+1, 1); MM1(4*(qi)+1, 2*(qj)+1, 1);                  \
    MM1(4*(qi)+2, 2*(qj)+1, 1); MM1(4*(qi)+3, 2*(qj)+1, 1);                  \
  } while (0)
#define BAR()    __builtin_amdgcn_s_barrier()
#define SCHEDB() __builtin_amdgcn_sched_barrier(0)
#define PRIO(p)  __builtin_amdgcn_s_setprio(p)

  // ---- prologue: K-tile 0 fully + A0 of K-tile 1 (10 loads/thread)
  STAGE_A(0, 0); STAGE_A(0, 1); STAGE_B(0, 0); STAGE_B(0, 1);
  STAGE_A(1, 0);
  asm volatile("s_waitcnt vmcnt(2)" ::: "memory");   // K0 landed; A0(1) flies
  BAR(); SCHEDB();

  // ---- main loop: 7 iters x 2 K-tiles; steady vmcnt(2) at K-tile bounds
#pragma unroll 1
  for (int it = 0; it < 7; ++it) {
    const int k1 = 2 * it + 1;   // staged at p0-p2 (buf1)
    const int k2 = 2 * it + 2;   // staged at p3-p6 (buf0)
    const int k3 = 2 * it + 3;   // A0 staged at p7 (buf1)
    // phase 0: K-tile 2it quad (0,0)
    LOAD_A(0, 0); LOAD_B(0, 0);
    STAGE_A(k1, 1);
    BAR(); SCHEDB(); PRIO(1); MFMA_Q(0, 0); PRIO(0); BAR(); SCHEDB();
    // phase 1: quad (0,1)
    LOAD_B(0, 1);
    STAGE_B(k1, 0);
    BAR(); SCHEDB(); PRIO(1); MFMA_Q(0, 1); PRIO(0); BAR(); SCHEDB();
    // phase 2: quad (1,1)
    LOAD_A(0, 1);
    STAGE_B(k1, 1);
    BAR(); SCHEDB(); PRIO(1); MFMA_Q(1, 1); PRIO(0); BAR(); SCHEDB();
    // phase 3: quad (1,0)  [K-tile boundary after]
    LOAD_B(0, 0);
    STAGE_A(k2, 0);
    BAR(); SCHEDB(); PRIO(1); MFMA_Q(1, 0); PRIO(0);
    asm volatile("s_waitcnt vmcnt(2)" ::: "memory");
    BAR(); SCHEDB();
    // phase 4: K-tile 2it+1 quad (0,0)
    LOAD_A(1, 0); LOAD_B(1, 0);
    STAGE_A(k2, 1);
    BAR(); SCHEDB(); PRIO(1); MFMA_Q(0, 0); PRIO(0); BAR(); SCHEDB();
    // phase 5: quad (0,1)
    LOAD_B(1, 1);
    STAGE_B(k2, 0);
    BAR(); SCHEDB(); PRIO(1); MFMA_Q(0, 1); PRIO(0); BAR(); SCHEDB();
    // phase 6: quad (1,1)
    LOAD_A(1, 1);
    STAGE_B(k2, 1);
    BAR(); SCHEDB(); PRIO(1); MFMA_Q(1, 1); PRIO(0); BAR(); SCHEDB();
    // phase 7: quad (1,0)  [K-tile boundary after]
    LOAD_B(1, 0);
    STAGE_A(k3, 0);
    BAR(); SCHEDB(); PRIO(1); MFMA_Q(1, 0); PRIO(0);
    asm volatile("s_waitcnt vmcnt(2)" ::: "memory");
    BAR(); SCHEDB();
  }

  // ---- peeled last iteration (K-tiles 14,15): stages clamped, drain at p3
  {
    // phase 0
    LOAD_A(0, 0); LOAD_B(0, 0);
    STAGE_A(15, 1);
    BAR(); SCHEDB(); PRIO(1); MFMA_Q(0, 0); PRIO(0); BAR(); SCHEDB();
    // phase 1
    LOAD_B(0, 1);
    STAGE_B(15, 0);
    BAR(); SCHEDB(); PRIO(1); MFMA_Q(0, 1); PRIO(0); BAR(); SCHEDB();
    // phase 2
    LOAD_A(0, 1);
    STAGE_B(15, 1);
    BAR(); SCHEDB(); PRIO(1); MFMA_Q(1, 1); PRIO(0); BAR(); SCHEDB();
    // phase 3 — drain: nothing staged after B1(15), so vmcnt(0) here
    LOAD_B(0, 0);
    BAR(); SCHEDB(); PRIO(1); MFMA_Q(1, 0); PRIO(0);
    asm volatile("s_waitcnt vmcnt(0)" ::: "memory");
    BAR(); SCHEDB();
    // phases 4-7: compute K-tile 15, no staging
    LOAD_A(1, 0); LOAD_B(1, 0);
    BAR(); SCHEDB(); PRIO(1); MFMA_Q(0, 0); PRIO(0); BAR(); SCHEDB();
    LOAD_B(1, 1);
    BAR(); SCHEDB(); PRIO(1); MFMA_Q(0, 1); PRIO(0); BAR(); SCHEDB();
    LOAD_A(1, 1);
    BAR(); SCHEDB(); PRIO(1); MFMA_Q(1, 1); PRIO(0); BAR(); SCHEDB();
    LOAD_B(1, 0);
    BAR(); SCHEDB(); PRIO(1); MFMA_Q(1, 0); PRIO(0); BAR(); SCHEDB();
  }

#undef STAGE_A
#undef STAGE_B
#undef LOAD_A
#undef LOAD_B
#undef MM1
#undef MFMA_Q
#undef BAR
#undef SCHEDB
#undef PRIO

  // ---- epilogue: two 128-row half-passes through T[128][264] (RoPE by<8)
  bf16* T = (bf16*)smem;
  __syncthreads();
#pragma unroll 1
  for (int hw = 0; hw < 2; ++hw) {
    if (wm == hw) {
#pragma unroll
      for (int rf = 0; rf < 8; ++rf)
#pragma unroll
        for (int cf = 0; cf < 4; ++cf)
#pragma unroll
          for (int r = 0; r < 4; ++r)
            T[(rf * 16 + fq * 4 + r) * 264 + wn * 64 + cf * 16 + fm] =
                (bf16)acc[rf][cf][r];
    }
    __syncthreads();
    if (by < 8) {  // q|k region: RoPE pair rotation in LDS
#pragma unroll
      for (int ii = 0; ii < 32; ++ii) {
        const int pi = t + ii * 512;            // 16384 pairs
        const int row = pi >> 7, pr = pi & 127;
        const int hd = pr >> 6, i = pr & 63;
        const int c0 = hd * 128 + i;
        const int s = (int)((m0 + hw * 128 + row) & 4095);
        const float2 sc = tab[s * 64 + i];
        float x1 = (float)T[row * 264 + c0];
        float x2 = (float)T[row * 264 + c0 + 64];
        T[row * 264 + c0]      = (bf16)(x1 * sc.y - x2 * sc.x);
        T[row * 264 + c0 + 64] = (bf16)(x2 * sc.y + x1 * sc.x);
      }
      __syncthreads();
    }
    // coalesced store: 128 rows x 512B
#pragma unroll
    for (int ii = 0; ii < 8; ++ii) {
      const int cid = t + ii * 512;
      const int row = cid >> 5, ch = cid & 31;
      *(bf16x8*)(C + (m0 + hw * 128 + row) * 4096 + n0 + ch * 8) =
          *(const bf16x8*)(T + row * 264 + ch * 8);
    }
    __syncthreads();
  }
}

// ---------------------------------------------------------------------------
// Final NT GEMM: out = obuf @ Wo^T, fp32 out. 1D grid 1024, XCD-swizzled.
// ---------------------------------------------------------------------------
__global__ __launch_bounds__(256, 2) void gemm_final(
    const bf16* __restrict__ A, const bf16* __restrict__ Bw,
    float* __restrict__ C)
{
  __shared__ __align__(16) bf16 As[128 * 32];
  __shared__ __align__(16) bf16 Bs[128 * 32];
  const int t = threadIdx.x;
  const int bid = blockIdx.x;
  const int xcd = bid & 7, n = bid >> 3;
  const int bx = xcd * 16 + (n & 15);
  const int by = n >> 4;
  const long m0 = (long)bx * 128;
  A  += m0 * 1024;
  Bw += (long)by * 131072;
  C  += m0 * 1024 + (long)by * 128;

  const int i0 = t, i1 = t + 256;
  const bf16* gA0 = A  + (long)(i0 >> 2) * 1024 + (i0 & 3) * 8;
  const bf16* gA1 = A  + (long)(i1 >> 2) * 1024 + (i1 & 3) * 8;
  const bf16* gB0 = Bw + (long)(i0 >> 2) * 1024 + (i0 & 3) * 8;
  const bf16* gB1 = Bw + (long)(i1 >> 2) * 1024 + (i1 & 3) * 8;
  bf16* lA0 = As + i0 * 8; bf16* lA1 = As + i1 * 8;
  bf16* lB0 = Bs + i0 * 8; bf16* lB1 = Bs + i1 * 8;

  const int lane = t & 63, wv = t >> 6;
  const int moff = (wv & 1) * 64, noff = (wv >> 1) * 64;
  const int fm = lane & 15, fq = lane >> 4;

  f32x4 acc[4][4] = {};

  for (int k0 = 0; k0 < 1024; k0 += 32) {
    async_copy16(gA0, lA0); async_copy16(gA1, lA1);
    async_copy16(gB0, lB0); async_copy16(gB1, lB1);
    gA0 += 32; gA1 += 32; gB0 += 32; gB1 += 32;
    __syncthreads();
    bf16x8 af[4], bfv[4];
#pragma unroll
    for (int i = 0; i < 4; ++i) {
      af[i]  = *(const bf16x8*)(As + (moff + i * 16 + fm) * 32 + fq * 8);
      bfv[i] = *(const bf16x8*)(Bs + (noff + i * 16 + fm) * 32 + fq * 8);
    }
#pragma unroll
    for (int i = 0; i < 4; ++i)
#pragma unroll
      for (int j = 0; j < 4; ++j)
        acc[i][j] = __builtin_amdgcn_mfma_f32_16x16x32_bf16(af[i], bfv[j], acc[i][j], 0, 0, 0);
    __syncthreads();
  }

#pragma unroll
  for (int i = 0; i < 4; ++i)
#pragma unroll
    for (int j = 0; j < 4; ++j)
#pragma unroll
      for (int r = 0; r < 4; ++r)
        C[(long)(moff + i * 16 + fq * 4 + r) * 1024 + noff + j * 16 + fm] = acc[i][j][r];
}

// ---------------------------------------------------------------------------
// num GEMM (per b,h: M=4096 N=128 K=128) + fused den + mala/LePE/gate.
// Half-tile epilogue (T = 64x136) for occupancy.
// ---------------------------------------------------------------------------
__global__ __launch_bounds__(256, 2) void gemm_num(
    const bf16* __restrict__ QKVG, const bf16* __restrict__ kvTall,
    const float* __restrict__ ksum, const float* __restrict__ vsum,
    const float* __restrict__ lepe_w, const float* __restrict__ lepe_b,
    bf16* __restrict__ obuf)
{
  __shared__ __align__(16) char smem[17408];
  bf16* As = (bf16*)smem;
  bf16* Bs = (bf16*)(smem + 8192);
  bf16* T  = (bf16*)smem;                      // epilogue, 64 rows, stride 136
  __shared__ float sden[128], svsum[128], slb[128], sksum[128];
  __shared__ float slw[5][128];

  const int t = threadIdx.x;
  const int h = blockIdx.y, b = blockIdx.z;
  const int bh = b * 8 + h;
  const long m0 = (long)blockIdx.x * 128;
  const bf16* A  = QKVG + (long)b * 16777216 + m0 * 4096 + h * 128;
  const bf16* Bw = kvTall + (long)bh * 16384;

  if (t < 128) {
    sksum[t] = ksum[bh * 128 + t];
    svsum[t] = vsum[bh * 128 + t];
    slb[t]   = lepe_b[h * 128 + t];
#pragma unroll
    for (int j = 0; j < 5; ++j) slw[j][t] = lepe_w[(h * 128 + t) * 5 + j];
  }

  const int i0 = t, i1 = t + 256;
  const bf16* gA0 = A + (long)(i0 >> 2) * 4096 + (i0 & 3) * 8;
  const bf16* gA1 = A + (long)(i1 >> 2) * 4096 + (i1 & 3) * 8;
  const bf16* gB0 = Bw + (long)(i0 >> 2) * 128 + (i0 & 3) * 8;
  const bf16* gB1 = Bw + (long)(i1 >> 2) * 128 + (i1 & 3) * 8;
  bf16* lA0 = As + i0 * 8; bf16* lA1 = As + i1 * 8;
  bf16* lB0 = Bs + i0 * 8; bf16* lB1 = Bs + i1 * 8;

  const int lane = t & 63, wv = t >> 6;
  const int moff = (wv & 1) * 64, noff = (wv >> 1) * 64;
  const int fm = lane & 15, fq = lane >> 4;

  f32x4 acc[4][4] = {};
  float dacc = 0.f;

  for (int k0 = 0; k0 < 128; k0 += 32) {
    async_copy16(gA0, lA0); async_copy16(gA1, lA1);
    async_copy16(gB0, lB0); async_copy16(gB1, lB1);
    gA0 += 32; gA1 += 32; gB0 += 32; gB1 += 32;
    __syncthreads();
    bf16x8 af[4], bfv[4];
#pragma unroll
    for (int i = 0; i < 4; ++i) {
      af[i]  = *(const bf16x8*)(As + (moff + i * 16 + fm) * 32 + fq * 8);
      bfv[i] = *(const bf16x8*)(Bs + (noff + i * 16 + fm) * 32 + fq * 8);
    }
#pragma unroll
    for (int i = 0; i < 4; ++i)
#pragma unroll
      for (int j = 0; j < 4; ++j)
        acc[i][j] = __builtin_amdgcn_mfma_f32_16x16x32_bf16(af[i], bfv[j], acc[i][j], 0, 0, 0);
    if (t < 128) {                 // den partial: row t, k-chunk k0..k0+32
#pragma unroll
      for (int c8 = 0; c8 < 4; ++c8) {
        bf16x8 q8 = *(const bf16x8*)(As + t * 32 + c8 * 8);
#pragma unroll
        for (int e = 0; e < 8; ++e) dacc += (float)q8[e] * sksum[k0 + c8 * 8 + e];
      }
    }
    __syncthreads();
  }
  if (t < 128) sden[t] = dacc * kScale + 4096.0f;

  const int c2 = lane * 2;
  const float w0[5] = {slw[0][c2], slw[1][c2], slw[2][c2], slw[3][c2], slw[4][c2]};
  const float w1[5] = {slw[0][c2+1], slw[1][c2+1], slw[2][c2+1], slw[3][c2+1], slw[4][c2+1]};
  const float lb0 = slb[c2], lb1 = slb[c2 + 1];

#pragma unroll
  for (int half = 0; half < 2; ++half) {
    if ((wv & 1) == half) {
#pragma unroll
      for (int i = 0; i < 4; ++i)
#pragma unroll
        for (int j = 0; j < 4; ++j)
#pragma unroll
          for (int r = 0; r < 4; ++r) {
            const int col = noff + j * 16 + fm;
            T[(i * 16 + fq * 4 + r) * 136 + col] = (bf16)(acc[i][j][r] * kScale + svsum[col]);
          }
    }
    __syncthreads();   // covers T (and sden on first pass)
    for (int rr = 0; rr < 16; ++rr) {
      const int lrow = wv * 16 + rr;           // 0..63
      const int row = half * 64 + lrow;        // 0..127 within tile
      const int s = (int)(m0 + row);
      const long grow = (long)b * 4096 + s;
      const float rden = 1.0f / sden[row];
      const bf16* vrow = QKVG + grow * 4096 + 2048 + h * 128 + c2;
      bf16x2 a2 = *(const bf16x2*)(T + lrow * 136 + c2);
      float lep0 = lb0, lep1 = lb1;
#pragma unroll
      for (int jt = 0; jt < 5; ++jt) {
        const int srow = s + jt - 2;
        if (srow >= 0 && srow < 4096) {        // wave-uniform branch
          bf16x2 v2 = *(const bf16x2*)(vrow + (long)(jt - 2) * 4096);
          lep0 += (float)v2[0] * w0[jt];
          lep1 += (float)v2[1] * w1[jt];
        }
      }
      bf16x2 g2 = *(const bf16x2*)(QKVG + grow * 4096 + 3072 + h * 128 + c2);
      bf16x2 o2;
      o2[0] = (bf16)(((float)a2[0] * rden + lep0) * (float)g2[0]);
      o2[1] = (bf16)(((float)a2[1] * rden + lep1) * (float)g2[1]);
      *(bf16x2*)(obuf + grow * 1024 + h * 128 + c2) = o2;
    }
    __syncthreads();
  }
}

// ---------------------------------------------------------------------------
// prep: cast X->bf16, cast/concat weights, build rope sin/cos table.
// ---------------------------------------------------------------------------
__global__ void prep_kernel(const float* __restrict__ X, const float* __restrict__ Wq,
                            const float* __restrict__ Wk, const float* __restrict__ Wv,
                            const float* __restrict__ Wg, const float* __restrict__ Wo,
                            bf16* __restrict__ Xb, bf16* __restrict__ Wcat,
                            bf16* __restrict__ Wob, float2* __restrict__ tab)
{
  const int blk = blockIdx.x;
  if (blk < 16384) {
    long g = ((long)blk * 256 + threadIdx.x) * 4;
    float4 v = *(const float4*)(X + g);
    bf16x4 o = {(bf16)v.x, (bf16)v.y, (bf16)v.z, (bf16)v.w};
    *(bf16x4*)(Xb + g) = o;
  } else if (blk < 21504) {
    long g = ((long)(blk - 16384) * 256 + threadIdx.x) * 4;
    if (g < 4194304) {
      long idx = g & 1048575;
      int sel = (int)(g >> 20);
      const float* s = sel == 0 ? Wq : sel == 1 ? Wk : sel == 2 ? Wv : Wg;
      float4 v = *(const float4*)(s + idx);
      bf16x4 o = {(bf16)v.x, (bf16)v.y, (bf16)v.z, (bf16)v.w};
      *(bf16x4*)(Wcat + g) = o;
    } else {
      long idx = g - 4194304;
      float4 v = *(const float4*)(Wo + idx);
      bf16x4 o = {(bf16)v.x, (bf16)v.y, (bf16)v.z, (bf16)v.w};
      *(bf16x4*)(Wob + idx) = o;
    }
  } else {
    int idx = (blk - 21504) * 256 + threadIdx.x;
    int s = idx >> 6, i = idx & 63;
    float inv = powf(10000.0f, -((float)(2 * i)) / 128.0f);
    float ang = (float)s * inv;
    float sn, cs;
    sincosf(ang, &sn, &cs);
    tab[idx] = make_float2(sn, cs);
  }
}

// ---------------------------------------------------------------------------
// kv via MFMA with in-LDS transpose. Grid (16, 32) = 512 blocks (2/CU).
// kvp[chunk][bh][e][d] = sum_s v[s][e] k[s][d]; + ksum/vsum partials.
// ---------------------------------------------------------------------------
__global__ __launch_bounds__(256, 2) void kv_mfma(
    const bf16* __restrict__ QKVG, float* __restrict__ kvp,
    float* __restrict__ ksump, float* __restrict__ vsump)
{
  __shared__ __align__(16) bf16 VT[128 * 40];
  __shared__ __align__(16) bf16 KT[128 * 40];
  const int t = threadIdx.x;
  const int chunk = blockIdx.x, bh = blockIdx.y;
  const int b = bh >> 3, h = bh & 7;
  const long rowbase = ((long)b * 4096 + chunk * 256) * 4096 + h * 128;
  const bf16* Kg = QKVG + rowbase + 1024;
  const bf16* Vg = QKVG + rowbase + 2048;

  const int sp = t >> 4, fc = t & 15;
  const int lane = t & 63, wv = t >> 6;
  const int eoff = (wv & 1) * 64, doff = (wv >> 1) * 64;
  const int fm = lane & 15, fq = lane >> 4;
  const int srow = t & 127;
  const bool sumK = t >= 128;

  f32x4 acc[4][4] = {};
  float rsum = 0.f;

  for (int sb = 0; sb < 256; sb += 32) {
    const long go = (long)(sb + 2 * sp) * 4096 + fc * 8;
    bf16x8 v0 = *(const bf16x8*)(Vg + go);
    bf16x8 v1 = *(const bf16x8*)(Vg + go + 4096);
    bf16x8 k0 = *(const bf16x8*)(Kg + go);
    bf16x8 k1 = *(const bf16x8*)(Kg + go + 4096);
#pragma unroll
    for (int j = 0; j < 8; ++j) {
      const int f = fc * 8 + j;
      bf16x2 vp2 = {v0[j], v1[j]};
      bf16x2 kp2 = {k0[j], k1[j]};
      *(bf16x2*)(VT + f * 40 + 2 * sp) = vp2;
      *(bf16x2*)(KT + f * 40 + 2 * sp) = kp2;
    }
    __syncthreads();
    bf16x8 af[4], bfv[4];
#pragma unroll
    for (int i = 0; i < 4; ++i) {
      af[i]  = *(const bf16x8*)(VT + (eoff + i * 16 + fm) * 40 + fq * 8);
      bfv[i] = *(const bf16x8*)(KT + (doff + i * 16 + fm) * 40 + fq * 8);
    }
#pragma unroll
    for (int i = 0; i < 4; ++i)
#pragma unroll
      for (int j = 0; j < 4; ++j)
        acc[i][j] = __builtin_amdgcn_mfma_f32_16x16x32_bf16(af[i], bfv[j], acc[i][j], 0, 0, 0);
    const bf16* rp = (sumK ? KT : VT) + srow * 40;
#pragma unroll
    for (int i = 0; i < 4; ++i) {
      bf16x8 r8 = *(const bf16x8*)(rp + i * 8);
#pragma unroll
      for (int j = 0; j < 8; ++j) rsum += (float)r8[j];
    }
    __syncthreads();
  }

  float* plane = kvp + ((long)chunk * 32 + bh) * 16384;
#pragma unroll
  for (int i = 0; i < 4; ++i)
#pragma unroll
    for (int j = 0; j < 4; ++j)
#pragma unroll
      for (int r = 0; r < 4; ++r)
        plane[(long)(eoff + i * 16 + fq * 4 + r) * 128 + (doff + j * 16 + fm)] = acc[i][j][r];
  float* sdst = (sumK ? ksump : vsump) + ((long)chunk * 32 + bh) * 128 + srow;
  *sdst = rsum;
}

// Fold 16 chunk partials -> bf16 kvT + f32 ksum/vsum.
__global__ void kv_reduce(const float* __restrict__ kvp, const float* __restrict__ ksump,
                          const float* __restrict__ vsump, bf16* __restrict__ kvT,
                          float* __restrict__ ksum, float* __restrict__ vsum)
{
  long g = (long)blockIdx.x * 256 + threadIdx.x;
  long bh = g >> 14, idx = g & 16383;
  float s = 0.f;
#pragma unroll
  for (int c = 0; c < 16; ++c) s += kvp[((long)c * 32 + bh) * 16384 + idx];
  kvT[g] = (bf16)s;
  if (g < 8192) {
    int bh2 = (int)(g >> 8), rem = (int)(g & 255), f = rem & 127;
    const float* src = (rem >> 7) ? ksump : vsump;
    float* dst = (rem >> 7) ? ksum : vsum;
    float s2 = 0.f;
#pragma unroll
    for (int c = 0; c < 16; ++c) s2 += src[((long)c * 32 + bh2) * 128 + f];
    dst[bh2 * 128 + f] = s2;
  }
}

// ---------------------------------------------------------------------------
extern "C" void kernel_launch(void* const* d_in, const int* in_sizes, int n_in,
                              void* d_out, int out_size, void* d_ws, size_t ws_size,
                              hipStream_t stream)
{
  const float* X      = (const float*)d_in[0];
  const float* Wq     = (const float*)d_in[1];
  const float* Wk     = (const float*)d_in[2];
  const float* Wv     = (const float*)d_in[3];
  const float* Wg     = (const float*)d_in[4];
  const float* Wo     = (const float*)d_in[5];
  const float* lepe_w = (const float*)d_in[6];
  const float* lepe_b = (const float*)d_in[7];
  float* out = (float*)d_out;

  char* ws = (char*)d_ws;
  bf16*   Xb    = (bf16*)(ws);
  float*  kvp   = (float*)(ws);                  // aliases Xb (dead after proj)
  bf16*   Wcat  = (bf16*)(ws + 33554432);
  bf16*   Wob   = (bf16*)(ws + 41943040);
  float2* tab   = (float2*)(ws + 44040192);
  float*  ksump = (float*)(ws + 44040192);       // aliases tab (dead after proj)
  float*  vsump = (float*)(ws + 44302336);
  bf16*   QKVG  = (bf16*)(ws + 46137344);
  float*  ksum  = (float*)(ws + 180355072);
  float*  vsum  = (float*)(ws + 180371456);
  bf16*   kvT   = (bf16*)(ws + 180387840);
  bf16*   obuf  = (bf16*)(ws + 181960704);

  prep_kernel<<<22528, 256, 0, stream>>>(X, Wq, Wk, Wv, Wg, Wo, Xb, Wcat, Wob, tab);

  gemm_qkvg<<<1024, 512, 0, stream>>>(Xb, Wcat, QKVG, tab);

  kv_mfma<<<dim3(16, 32), 256, 0, stream>>>(QKVG, kvp, ksump, vsump);
  kv_reduce<<<2048, 256, 0, stream>>>(kvp, ksump, vsump, kvT, ksum, vsum);

  gemm_num<<<dim3(32, 8, 4), 256, 0, stream>>>(QKVG, kvT, ksum, vsum, lepe_w, lepe_b, obuf);

  gemm_final<<<1024, 256, 0, stream>>>(obuf, Wob, out);
}

// Round 3
// 427.406 us; speedup vs baseline: 1.0593x; 1.0593x over previous
//
#include <hip/hip_runtime.h>
#include <math.h>
#include <stdint.h>

// ---------------------------------------------------------------------------
// MalaAttention on MI355X (gfx950). Round 8:
//  - gemm_qkvg 256x256 8-phase: FIX swizzle to full 3-bit T2 form
//    (byte ^= (row&7)<<4; ks-step applied inside the XOR via o0/o1),
//    B fragments resident per K-tile (b4[4][2], phases 3/7 have 0 ds_reads),
//    XCD mapping restored to m-partitioned (8 m-tiles/XCD, A panel ~L2).
//  - all other kernels unchanged.
//
// Workspace layout (bytes):
//   Xb    @ 0          32MB  bf16 X        (dead after proj -> kvp)
//   kvp   @ 0          32MB  f32 [16][bh][128][128] kv partials
//   Wcat  @ 33554432    8MB  bf16 [Wq;Wk;Wv;Wg]
//   Wob   @ 41943040    2MB  bf16 Wo
//   tab   @ 44040192    2MB  float2 [4096][64] rope sin/cos (dead after proj)
//   ksump @ 44040192  256KB  f32 [16][bh][128]   (aliases tab)
//   vsump @ 44302336  256KB  f32 [16][bh][128]
//   QKVG  @ 46137344  128MB  bf16 [16384][4096] col blocks: q|k|v|g
//   ksum  @ 180355072  16KB  f32 [bh][128]
//   vsum  @ 180371456  16KB  f32 [bh][128]
//   kvT   @ 180387840   1MB  bf16 kvT[bh][e][d]
//   obuf  @ 181960704  32MB  bf16 gated out
// ---------------------------------------------------------------------------

typedef __bf16 bf16;
typedef __bf16 bf16x2 __attribute__((ext_vector_type(2)));
typedef __bf16 bf16x4 __attribute__((ext_vector_type(4)));
typedef __bf16 bf16x8 __attribute__((ext_vector_type(8)));
typedef float f32x4 __attribute__((ext_vector_type(4)));

static constexpr float kScale = 0.08838834764831845f; // 1/sqrt(128)

__device__ __forceinline__ void async_copy16(const void* g, void* l) {
  __builtin_amdgcn_global_load_lds(
      (const __attribute__((address_space(1))) void*)(uintptr_t)g,
      (__attribute__((address_space(3))) void*)(uintptr_t)l, 16, 0, 0);
}

// ---------------------------------------------------------------------------
// Proj GEMM: QKVG = Xb @ Wcat^T. 256x256 tile, BK=64, 8-phase schedule.
// Grid 1024 (64 m-tiles x 16 n-tiles), XCD m-partitioned. RoPE fused (by<8).
// ---------------------------------------------------------------------------
__global__ __launch_bounds__(512, 1) void gemm_qkvg(
    const bf16* __restrict__ A, const bf16* __restrict__ Bw,
    bf16* __restrict__ C, const float2* __restrict__ tab)
{
  // LDS: buf b at b*65536; within buf: A-half h at h*16384, B-half h at
  // 32768 + h*16384. Each half-tile: [128 rows][64 k] bf16 = 16KB, stored
  // LINEARLY (global_load_lds) with pre-swizzled global source; logical
  // byte <-> physical byte via involution  p = l ^ (((l>>7)&7)<<4)
  // (T2: 16B-slot index XORed with row&7 -> conflict-free ds_read_b128).
  __shared__ __align__(16) char smem[131072];

  const int t = threadIdx.x;
  const int bid = blockIdx.x;
  const int n = bid >> 3;
  const int bx = (bid & 7) * 8 + (n & 7);         // 8 m-tiles per XCD
  const int by = n >> 3;                          // 0..15
  const long m0 = (long)bx * 256;
  const long n0 = (long)by * 256;

  // ---- staging addressing (pre-swizzled global source, linear LDS dest)
  const int d0 = t * 16;                          // physical byte in half-tile
  const int dd = d0 ^ (((d0 >> 7) & 7) << 4);     // logical byte offset
  const int rT = dd >> 7;                         // logical row 0..63
  const int cT = (dd & 127) >> 1;                 // element col
  const bf16* aSt = A  + (m0 + rT) * 1024 + cT;
  const bf16* bSt = Bw + (n0 + rT) * 1024 + cT;
  char* ldsDst = smem + d0;

  // ---- fragment read addressing (swizzled; ks-step inside the XOR)
  const int lane = t & 63, wid = t >> 6;
  const int wm = wid >> 2, wn = wid & 3;          // 2Mx4N waves
  const int fm = lane & 15, fq = lane >> 4;
  const int xsw = (fm & 7) << 4;
  const int o0 = (fq * 16) ^ xsw;                 // ks=0 col bytes
  const int o1 = o0 ^ 64;                         // ks=1 col bytes
  const char* ldsA0 = smem + wm * 16384 + fm * 128 + o0;
  const char* ldsA1 = smem + wm * 16384 + fm * 128 + o1;
  const char* ldsB0 = smem + 32768 + (wn >> 1) * 16384 +
                      ((wn & 1) * 64 + fm) * 128 + o0;
  const char* ldsB1 = ldsB0 + (o1 - o0);

  f32x4 acc[8][4] = {};
  bf16x8 a4[4][2], b4[4][2];

#define STAGE_A(kt, h) do {                                                  \
    const bf16* s_ = aSt + (long)(h) * 131072 + (kt) * 64;                   \
    char* d_ = ldsDst + ((kt) & 1) * 65536 + (h) * 16384;                    \
    async_copy16(s_, d_);                                                    \
    async_copy16(s_ + 65536, d_ + 8192);                                     \
  } while (0)
#define STAGE_B(kt, h) do {                                                  \
    const bf16* s_ = bSt + (long)(h) * 131072 + (kt) * 64;                   \
    char* d_ = ldsDst + ((kt) & 1) * 65536 + 32768 + (h) * 16384;            \
    async_copy16(s_, d_);                                                    \
    async_copy16(s_ + 65536, d_ + 8192);                                     \
  } while (0)
#define LOAD_A(buf, qi) do {                                                 \
    const char* p0_ = ldsA0 + (buf) * 65536 + (qi) * 8192;                   \
    const char* p1_ = ldsA1 + (buf) * 65536 + (qi) * 8192;                   \
    a4[0][0] = *(const bf16x8*)(p0_);                                        \
    a4[0][1] = *(const bf16x8*)(p1_);                                        \
    a4[1][0] = *(const bf16x8*)(p0_ + 2048);                                 \
    a4[1][1] = *(const bf16x8*)(p1_ + 2048);                                 \
    a4[2][0] = *(const bf16x8*)(p0_ + 4096);                                 \
    a4[2][1] = *(const bf16x8*)(p1_ + 4096);                                 \
    a4[3][0] = *(const bf16x8*)(p0_ + 6144);                                 \
    a4[3][1] = *(const bf16x8*)(p1_ + 6144);                                 \
  } while (0)
#define LOAD_B(buf, qj) do {                                                 \
    const char* p0_ = ldsB0 + (buf) * 65536 + (qj) * 4096;                   \
    const char* p1_ = ldsB1 + (buf) * 65536 + (qj) * 4096;                   \
    b4[2*(qj)+0][0] = *(const bf16x8*)(p0_);                                 \
    b4[2*(qj)+0][1] = *(const bf16x8*)(p1_);                                 \
    b4[2*(qj)+1][0] = *(const bf16x8*)(p0_ + 2048);                          \
    b4[2*(qj)+1][1] = *(const bf16x8*)(p1_ + 2048);                          \
  } while (0)
#define MM1(i, j, ks)                                                        \
    acc[i][j] = __builtin_amdgcn_mfma_f32_16x16x32_bf16(                     \
        a4[(i) & 3][ks], b4[j][ks], acc[i][j], 0, 0, 0)
#define MFMA_Q(qi, qj) do {                                                  \
    MM1(4*(qi)+0, 2*(qj)+0, 0); MM1(4*(qi)+1, 2*(qj)+0, 0);                  \
    MM1(4*(qi)+2, 2*(qj)+0, 0); MM1(4*(qi)+3, 2*(qj)+0, 0);                  \
    MM1(4*(qi)+0, 2*(qj)+1, 0); MM1(4*(qi)+1, 2*(qj)+1, 0);                  \
    MM1(4*(qi)+2, 2*(qj)+1, 0); MM1(4*(qi)+3, 2*(qj)+1, 0);                  \
    MM1(4*(qi)+0, 2*(qj)+0, 1); MM1(4*(qi)+1, 2*(qj)+0, 1);                  \
    MM1(4*(qi)+2, 2*(qj)+0, 1); MM1(4*(qi)+3, 2*(qj)+0, 1);                  \
    MM1(4*(qi)+0, 2*(qj)+1, 1); MM1(4*(qi)+1, 2*(qj)+1, 1);                  \
    MM1(4*(qi)+2, 2*(qj)+1, 1); MM1(4*(qi)+3, 2*(qj)+1, 1);                  \
  } while (0)
#define BAR()    __builtin_amdgcn_s_barrier()
#define SCHEDB() __builtin_amdgcn_sched_barrier(0)
#define PRIO(p)  __builtin_amdgcn_s_setprio(p)

  // ---- prologue: K-tile 0 fully + A0 of K-tile 1 (10 loads/thread)
  STAGE_A(0, 0); STAGE_A(0, 1); STAGE_B(0, 0); STAGE_B(0, 1);
  STAGE_A(1, 0);
  asm volatile("s_waitcnt vmcnt(2)" ::: "memory");   // K0 landed; A0(1) flies
  BAR(); SCHEDB();

  // ---- main loop: 7 iters x 2 K-tiles; steady vmcnt(2) at K-tile bounds
#pragma unroll 1
  for (int it = 0; it < 7; ++it) {
    const int k1 = 2 * it + 1;   // staged at p0-p2 (buf1)
    const int k2 = 2 * it + 2;   // staged at p3-p6 (buf0)
    const int k3 = 2 * it + 3;   // A0 staged at p7 (buf1)
    // phase 0: K-tile 2it quad (0,0)
    LOAD_A(0, 0); LOAD_B(0, 0);
    STAGE_A(k1, 1);
    BAR(); SCHEDB(); PRIO(1); MFMA_Q(0, 0); PRIO(0); BAR(); SCHEDB();
    // phase 1: quad (0,1)
    LOAD_B(0, 1);
    STAGE_B(k1, 0);
    BAR(); SCHEDB(); PRIO(1); MFMA_Q(0, 1); PRIO(0); BAR(); SCHEDB();
    // phase 2: quad (1,1)  (b4[2],[3] resident)
    LOAD_A(0, 1);
    STAGE_B(k1, 1);
    BAR(); SCHEDB(); PRIO(1); MFMA_Q(1, 1); PRIO(0); BAR(); SCHEDB();
    // phase 3: quad (1,0)  (b4[0],[1] resident)  [K-tile boundary after]
    STAGE_A(k2, 0);
    BAR(); SCHEDB(); PRIO(1); MFMA_Q(1, 0); PRIO(0);
    asm volatile("s_waitcnt vmcnt(2)" ::: "memory");
    BAR(); SCHEDB();
    // phase 4: K-tile 2it+1 quad (0,0)
    LOAD_A(1, 0); LOAD_B(1, 0);
    STAGE_A(k2, 1);
    BAR(); SCHEDB(); PRIO(1); MFMA_Q(0, 0); PRIO(0); BAR(); SCHEDB();
    // phase 5: quad (0,1)
    LOAD_B(1, 1);
    STAGE_B(k2, 0);
    BAR(); SCHEDB(); PRIO(1); MFMA_Q(0, 1); PRIO(0); BAR(); SCHEDB();
    // phase 6: quad (1,1)
    LOAD_A(1, 1);
    STAGE_B(k2, 1);
    BAR(); SCHEDB(); PRIO(1); MFMA_Q(1, 1); PRIO(0); BAR(); SCHEDB();
    // phase 7: quad (1,0)  [K-tile boundary after]
    STAGE_A(k3, 0);
    BAR(); SCHEDB(); PRIO(1); MFMA_Q(1, 0); PRIO(0);
    asm volatile("s_waitcnt vmcnt(2)" ::: "memory");
    BAR(); SCHEDB();
  }

  // ---- peeled last iteration (K-tiles 14,15): stages clamped, drain at p3
  {
    // phase 0
    LOAD_A(0, 0); LOAD_B(0, 0);
    STAGE_A(15, 1);
    BAR(); SCHEDB(); PRIO(1); MFMA_Q(0, 0); PRIO(0); BAR(); SCHEDB();
    // phase 1
    LOAD_B(0, 1);
    STAGE_B(15, 0);
    BAR(); SCHEDB(); PRIO(1); MFMA_Q(0, 1); PRIO(0); BAR(); SCHEDB();
    // phase 2
    LOAD_A(0, 1);
    STAGE_B(15, 1);
    BAR(); SCHEDB(); PRIO(1); MFMA_Q(1, 1); PRIO(0); BAR(); SCHEDB();
    // phase 3 — drain: nothing staged after B1(15), so vmcnt(0) here
    BAR(); SCHEDB(); PRIO(1); MFMA_Q(1, 0); PRIO(0);
    asm volatile("s_waitcnt vmcnt(0)" ::: "memory");
    BAR(); SCHEDB();
    // phases 4-7: compute K-tile 15, no staging
    LOAD_A(1, 0); LOAD_B(1, 0);
    BAR(); SCHEDB(); PRIO(1); MFMA_Q(0, 0); PRIO(0); BAR(); SCHEDB();
    LOAD_B(1, 1);
    BAR(); SCHEDB(); PRIO(1); MFMA_Q(0, 1); PRIO(0); BAR(); SCHEDB();
    LOAD_A(1, 1);
    BAR(); SCHEDB(); PRIO(1); MFMA_Q(1, 1); PRIO(0); BAR(); SCHEDB();
    BAR(); SCHEDB(); PRIO(1); MFMA_Q(1, 0); PRIO(0); BAR(); SCHEDB();
  }

#undef STAGE_A
#undef STAGE_B
#undef LOAD_A
#undef LOAD_B
#undef MM1
#undef MFMA_Q
#undef BAR
#undef SCHEDB
#undef PRIO

  // ---- epilogue: two 128-row half-passes through T[128][264] (RoPE by<8)
  bf16* T = (bf16*)smem;
  __syncthreads();
#pragma unroll 1
  for (int hw = 0; hw < 2; ++hw) {
    if (wm == hw) {
#pragma unroll
      for (int rf = 0; rf < 8; ++rf)
#pragma unroll
        for (int cf = 0; cf < 4; ++cf)
#pragma unroll
          for (int r = 0; r < 4; ++r)
            T[(rf * 16 + fq * 4 + r) * 264 + wn * 64 + cf * 16 + fm] =
                (bf16)acc[rf][cf][r];
    }
    __syncthreads();
    if (by < 8) {  // q|k region: RoPE pair rotation in LDS
#pragma unroll
      for (int ii = 0; ii < 32; ++ii) {
        const int pi = t + ii * 512;            // 16384 pairs
        const int row = pi >> 7, pr = pi & 127;
        const int hd = pr >> 6, i = pr & 63;
        const int c0 = hd * 128 + i;
        const int s = (int)((m0 + hw * 128 + row) & 4095);
        const float2 sc = tab[s * 64 + i];
        float x1 = (float)T[row * 264 + c0];
        float x2 = (float)T[row * 264 + c0 + 64];
        T[row * 264 + c0]      = (bf16)(x1 * sc.y - x2 * sc.x);
        T[row * 264 + c0 + 64] = (bf16)(x2 * sc.y + x1 * sc.x);
      }
      __syncthreads();
    }
    // coalesced store: 128 rows x 512B
#pragma unroll
    for (int ii = 0; ii < 8; ++ii) {
      const int cid = t + ii * 512;
      const int row = cid >> 5, ch = cid & 31;
      *(bf16x8*)(C + (m0 + hw * 128 + row) * 4096 + n0 + ch * 8) =
          *(const bf16x8*)(T + row * 264 + ch * 8);
    }
    __syncthreads();
  }
}

// ---------------------------------------------------------------------------
// Final NT GEMM: out = obuf @ Wo^T, fp32 out. 1D grid 1024, XCD-swizzled.
// ---------------------------------------------------------------------------
__global__ __launch_bounds__(256, 2) void gemm_final(
    const bf16* __restrict__ A, const bf16* __restrict__ Bw,
    float* __restrict__ C)
{
  __shared__ __align__(16) bf16 As[128 * 32];
  __shared__ __align__(16) bf16 Bs[128 * 32];
  const int t = threadIdx.x;
  const int bid = blockIdx.x;
  const int xcd = bid & 7, n = bid >> 3;
  const int bx = xcd * 16 + (n & 15);
  const int by = n >> 4;
  const long m0 = (long)bx * 128;
  A  += m0 * 1024;
  Bw += (long)by * 131072;
  C  += m0 * 1024 + (long)by * 128;

  const int i0 = t, i1 = t + 256;
  const bf16* gA0 = A  + (long)(i0 >> 2) * 1024 + (i0 & 3) * 8;
  const bf16* gA1 = A  + (long)(i1 >> 2) * 1024 + (i1 & 3) * 8;
  const bf16* gB0 = Bw + (long)(i0 >> 2) * 1024 + (i0 & 3) * 8;
  const bf16* gB1 = Bw + (long)(i1 >> 2) * 1024 + (i1 & 3) * 8;
  bf16* lA0 = As + i0 * 8; bf16* lA1 = As + i1 * 8;
  bf16* lB0 = Bs + i0 * 8; bf16* lB1 = Bs + i1 * 8;

  const int lane = t & 63, wv = t >> 6;
  const int moff = (wv & 1) * 64, noff = (wv >> 1) * 64;
  const int fm = lane & 15, fq = lane >> 4;

  f32x4 acc[4][4] = {};

  for (int k0 = 0; k0 < 1024; k0 += 32) {
    async_copy16(gA0, lA0); async_copy16(gA1, lA1);
    async_copy16(gB0, lB0); async_copy16(gB1, lB1);
    gA0 += 32; gA1 += 32; gB0 += 32; gB1 += 32;
    __syncthreads();
    bf16x8 af[4], bfv[4];
#pragma unroll
    for (int i = 0; i < 4; ++i) {
      af[i]  = *(const bf16x8*)(As + (moff + i * 16 + fm) * 32 + fq * 8);
      bfv[i] = *(const bf16x8*)(Bs + (noff + i * 16 + fm) * 32 + fq * 8);
    }
#pragma unroll
    for (int i = 0; i < 4; ++i)
#pragma unroll
      for (int j = 0; j < 4; ++j)
        acc[i][j] = __builtin_amdgcn_mfma_f32_16x16x32_bf16(af[i], bfv[j], acc[i][j], 0, 0, 0);
    __syncthreads();
  }

#pragma unroll
  for (int i = 0; i < 4; ++i)
#pragma unroll
    for (int j = 0; j < 4; ++j)
#pragma unroll
      for (int r = 0; r < 4; ++r)
        C[(long)(moff + i * 16 + fq * 4 + r) * 1024 + noff + j * 16 + fm] = acc[i][j][r];
}

// ---------------------------------------------------------------------------
// num GEMM (per b,h: M=4096 N=128 K=128) + fused den + mala/LePE/gate.
// Half-tile epilogue (T = 64x136) for occupancy.
// ---------------------------------------------------------------------------
__global__ __launch_bounds__(256, 2) void gemm_num(
    const bf16* __restrict__ QKVG, const bf16* __restrict__ kvTall,
    const float* __restrict__ ksum, const float* __restrict__ vsum,
    const float* __restrict__ lepe_w, const float* __restrict__ lepe_b,
    bf16* __restrict__ obuf)
{
  __shared__ __align__(16) char smem[17408];
  bf16* As = (bf16*)smem;
  bf16* Bs = (bf16*)(smem + 8192);
  bf16* T  = (bf16*)smem;                      // epilogue, 64 rows, stride 136
  __shared__ float sden[128], svsum[128], slb[128], sksum[128];
  __shared__ float slw[5][128];

  const int t = threadIdx.x;
  const int h = blockIdx.y, b = blockIdx.z;
  const int bh = b * 8 + h;
  const long m0 = (long)blockIdx.x * 128;
  const bf16* A  = QKVG + (long)b * 16777216 + m0 * 4096 + h * 128;
  const bf16* Bw = kvTall + (long)bh * 16384;

  if (t < 128) {
    sksum[t] = ksum[bh * 128 + t];
    svsum[t] = vsum[bh * 128 + t];
    slb[t]   = lepe_b[h * 128 + t];
#pragma unroll
    for (int j = 0; j < 5; ++j) slw[j][t] = lepe_w[(h * 128 + t) * 5 + j];
  }

  const int i0 = t, i1 = t + 256;
  const bf16* gA0 = A + (long)(i0 >> 2) * 4096 + (i0 & 3) * 8;
  const bf16* gA1 = A + (long)(i1 >> 2) * 4096 + (i1 & 3) * 8;
  const bf16* gB0 = Bw + (long)(i0 >> 2) * 128 + (i0 & 3) * 8;
  const bf16* gB1 = Bw + (long)(i1 >> 2) * 128 + (i1 & 3) * 8;
  bf16* lA0 = As + i0 * 8; bf16* lA1 = As + i1 * 8;
  bf16* lB0 = Bs + i0 * 8; bf16* lB1 = Bs + i1 * 8;

  const int lane = t & 63, wv = t >> 6;
  const int moff = (wv & 1) * 64, noff = (wv >> 1) * 64;
  const int fm = lane & 15, fq = lane >> 4;

  f32x4 acc[4][4] = {};
  float dacc = 0.f;

  for (int k0 = 0; k0 < 128; k0 += 32) {
    async_copy16(gA0, lA0); async_copy16(gA1, lA1);
    async_copy16(gB0, lB0); async_copy16(gB1, lB1);
    gA0 += 32; gA1 += 32; gB0 += 32; gB1 += 32;
    __syncthreads();
    bf16x8 af[4], bfv[4];
#pragma unroll
    for (int i = 0; i < 4; ++i) {
      af[i]  = *(const bf16x8*)(As + (moff + i * 16 + fm) * 32 + fq * 8);
      bfv[i] = *(const bf16x8*)(Bs + (noff + i * 16 + fm) * 32 + fq * 8);
    }
#pragma unroll
    for (int i = 0; i < 4; ++i)
#pragma unroll
      for (int j = 0; j < 4; ++j)
        acc[i][j] = __builtin_amdgcn_mfma_f32_16x16x32_bf16(af[i], bfv[j], acc[i][j], 0, 0, 0);
    if (t < 128) {                 // den partial: row t, k-chunk k0..k0+32
#pragma unroll
      for (int c8 = 0; c8 < 4; ++c8) {
        bf16x8 q8 = *(const bf16x8*)(As + t * 32 + c8 * 8);
#pragma unroll
        for (int e = 0; e < 8; ++e) dacc += (float)q8[e] * sksum[k0 + c8 * 8 + e];
      }
    }
    __syncthreads();
  }
  if (t < 128) sden[t] = dacc * kScale + 4096.0f;

  const int c2 = lane * 2;
  const float w0[5] = {slw[0][c2], slw[1][c2], slw[2][c2], slw[3][c2], slw[4][c2]};
  const float w1[5] = {slw[0][c2+1], slw[1][c2+1], slw[2][c2+1], slw[3][c2+1], slw[4][c2+1]};
  const float lb0 = slb[c2], lb1 = slb[c2 + 1];

#pragma unroll
  for (int half = 0; half < 2; ++half) {
    if ((wv & 1) == half) {
#pragma unroll
      for (int i = 0; i < 4; ++i)
#pragma unroll
        for (int j = 0; j < 4; ++j)
#pragma unroll
          for (int r = 0; r < 4; ++r) {
            const int col = noff + j * 16 + fm;
            T[(i * 16 + fq * 4 + r) * 136 + col] = (bf16)(acc[i][j][r] * kScale + svsum[col]);
          }
    }
    __syncthreads();   // covers T (and sden on first pass)
    for (int rr = 0; rr < 16; ++rr) {
      const int lrow = wv * 16 + rr;           // 0..63
      const int row = half * 64 + lrow;        // 0..127 within tile
      const int s = (int)(m0 + row);
      const long grow = (long)b * 4096 + s;
      const float rden = 1.0f / sden[row];
      const bf16* vrow = QKVG + grow * 4096 + 2048 + h * 128 + c2;
      bf16x2 a2 = *(const bf16x2*)(T + lrow * 136 + c2);
      float lep0 = lb0, lep1 = lb1;
#pragma unroll
      for (int jt = 0; jt < 5; ++jt) {
        const int srow = s + jt - 2;
        if (srow >= 0 && srow < 4096) {        // wave-uniform branch
          bf16x2 v2 = *(const bf16x2*)(vrow + (long)(jt - 2) * 4096);
          lep0 += (float)v2[0] * w0[jt];
          lep1 += (float)v2[1] * w1[jt];
        }
      }
      bf16x2 g2 = *(const bf16x2*)(QKVG + grow * 4096 + 3072 + h * 128 + c2);
      bf16x2 o2;
      o2[0] = (bf16)(((float)a2[0] * rden + lep0) * (float)g2[0]);
      o2[1] = (bf16)(((float)a2[1] * rden + lep1) * (float)g2[1]);
      *(bf16x2*)(obuf + grow * 1024 + h * 128 + c2) = o2;
    }
    __syncthreads();
  }
}

// ---------------------------------------------------------------------------
// prep: cast X->bf16, cast/concat weights, build rope sin/cos table.
// ---------------------------------------------------------------------------
__global__ void prep_kernel(const float* __restrict__ X, const float* __restrict__ Wq,
                            const float* __restrict__ Wk, const float* __restrict__ Wv,
                            const float* __restrict__ Wg, const float* __restrict__ Wo,
                            bf16* __restrict__ Xb, bf16* __restrict__ Wcat,
                            bf16* __restrict__ Wob, float2* __restrict__ tab)
{
  const int blk = blockIdx.x;
  if (blk < 16384) {
    long g = ((long)blk * 256 + threadIdx.x) * 4;
    float4 v = *(const float4*)(X + g);
    bf16x4 o = {(bf16)v.x, (bf16)v.y, (bf16)v.z, (bf16)v.w};
    *(bf16x4*)(Xb + g) = o;
  } else if (blk < 21504) {
    long g = ((long)(blk - 16384) * 256 + threadIdx.x) * 4;
    if (g < 4194304) {
      long idx = g & 1048575;
      int sel = (int)(g >> 20);
      const float* s = sel == 0 ? Wq : sel == 1 ? Wk : sel == 2 ? Wv : Wg;
      float4 v = *(const float4*)(s + idx);
      bf16x4 o = {(bf16)v.x, (bf16)v.y, (bf16)v.z, (bf16)v.w};
      *(bf16x4*)(Wcat + g) = o;
    } else {
      long idx = g - 4194304;
      float4 v = *(const float4*)(Wo + idx);
      bf16x4 o = {(bf16)v.x, (bf16)v.y, (bf16)v.z, (bf16)v.w};
      *(bf16x4*)(Wob + idx) = o;
    }
  } else {
    int idx = (blk - 21504) * 256 + threadIdx.x;
    int s = idx >> 6, i = idx & 63;
    float inv = powf(10000.0f, -((float)(2 * i)) / 128.0f);
    float ang = (float)s * inv;
    float sn, cs;
    sincosf(ang, &sn, &cs);
    tab[idx] = make_float2(sn, cs);
  }
}

// ---------------------------------------------------------------------------
// kv via MFMA with in-LDS transpose. Grid (16, 32) = 512 blocks (2/CU).
// kvp[chunk][bh][e][d] = sum_s v[s][e] k[s][d]; + ksum/vsum partials.
// ---------------------------------------------------------------------------
__global__ __launch_bounds__(256, 2) void kv_mfma(
    const bf16* __restrict__ QKVG, float* __restrict__ kvp,
    float* __restrict__ ksump, float* __restrict__ vsump)
{
  __shared__ __align__(16) bf16 VT[128 * 40];
  __shared__ __align__(16) bf16 KT[128 * 40];
  const int t = threadIdx.x;
  const int chunk = blockIdx.x, bh = blockIdx.y;
  const int b = bh >> 3, h = bh & 7;
  const long rowbase = ((long)b * 4096 + chunk * 256) * 4096 + h * 128;
  const bf16* Kg = QKVG + rowbase + 1024;
  const bf16* Vg = QKVG + rowbase + 2048;

  const int sp = t >> 4, fc = t & 15;
  const int lane = t & 63, wv = t >> 6;
  const int eoff = (wv & 1) * 64, doff = (wv >> 1) * 64;
  const int fm = lane & 15, fq = lane >> 4;
  const int srow = t & 127;
  const bool sumK = t >= 128;

  f32x4 acc[4][4] = {};
  float rsum = 0.f;

  for (int sb = 0; sb < 256; sb += 32) {
    const long go = (long)(sb + 2 * sp) * 4096 + fc * 8;
    bf16x8 v0 = *(const bf16x8*)(Vg + go);
    bf16x8 v1 = *(const bf16x8*)(Vg + go + 4096);
    bf16x8 k0 = *(const bf16x8*)(Kg + go);
    bf16x8 k1 = *(const bf16x8*)(Kg + go + 4096);
#pragma unroll
    for (int j = 0; j < 8; ++j) {
      const int f = fc * 8 + j;
      bf16x2 vp2 = {v0[j], v1[j]};
      bf16x2 kp2 = {k0[j], k1[j]};
      *(bf16x2*)(VT + f * 40 + 2 * sp) = vp2;
      *(bf16x2*)(KT + f * 40 + 2 * sp) = kp2;
    }
    __syncthreads();
    bf16x8 af[4], bfv[4];
#pragma unroll
    for (int i = 0; i < 4; ++i) {
      af[i]  = *(const bf16x8*)(VT + (eoff + i * 16 + fm) * 40 + fq * 8);
      bfv[i] = *(const bf16x8*)(KT + (doff + i * 16 + fm) * 40 + fq * 8);
    }
#pragma unroll
    for (int i = 0; i < 4; ++i)
#pragma unroll
      for (int j = 0; j < 4; ++j)
        acc[i][j] = __builtin_amdgcn_mfma_f32_16x16x32_bf16(af[i], bfv[j], acc[i][j], 0, 0, 0);
    const bf16* rp = (sumK ? KT : VT) + srow * 40;
#pragma unroll
    for (int i = 0; i < 4; ++i) {
      bf16x8 r8 = *(const bf16x8*)(rp + i * 8);
#pragma unroll
      for (int j = 0; j < 8; ++j) rsum += (float)r8[j];
    }
    __syncthreads();
  }

  float* plane = kvp + ((long)chunk * 32 + bh) * 16384;
#pragma unroll
  for (int i = 0; i < 4; ++i)
#pragma unroll
    for (int j = 0; j < 4; ++j)
#pragma unroll
      for (int r = 0; r < 4; ++r)
        plane[(long)(eoff + i * 16 + fq * 4 + r) * 128 + (doff + j * 16 + fm)] = acc[i][j][r];
  float* sdst = (sumK ? ksump : vsump) + ((long)chunk * 32 + bh) * 128 + srow;
  *sdst = rsum;
}

// Fold 16 chunk partials -> bf16 kvT + f32 ksum/vsum.
__global__ void kv_reduce(const float* __restrict__ kvp, const float* __restrict__ ksump,
                          const float* __restrict__ vsump, bf16* __restrict__ kvT,
                          float* __restrict__ ksum, float* __restrict__ vsum)
{
  long g = (long)blockIdx.x * 256 + threadIdx.x;
  long bh = g >> 14, idx = g & 16383;
  float s = 0.f;
#pragma unroll
  for (int c = 0; c < 16; ++c) s += kvp[((long)c * 32 + bh) * 16384 + idx];
  kvT[g] = (bf16)s;
  if (g < 8192) {
    int bh2 = (int)(g >> 8), rem = (int)(g & 255), f = rem & 127;
    const float* src = (rem >> 7) ? ksump : vsump;
    float* dst = (rem >> 7) ? ksum : vsum;
    float s2 = 0.f;
#pragma unroll
    for (int c = 0; c < 16; ++c) s2 += src[((long)c * 32 + bh2) * 128 + f];
    dst[bh2 * 128 + f] = s2;
  }
}

// ---------------------------------------------------------------------------
extern "C" void kernel_launch(void* const* d_in, const int* in_sizes, int n_in,
                              void* d_out, int out_size, void* d_ws, size_t ws_size,
                              hipStream_t stream)
{
  const float* X      = (const float*)d_in[0];
  const float* Wq     = (const float*)d_in[1];
  const float* Wk     = (const float*)d_in[2];
  const float* Wv     = (const float*)d_in[3];
  const float* Wg     = (const float*)d_in[4];
  const float* Wo     = (const float*)d_in[5];
  const float* lepe_w = (const float*)d_in[6];
  const float* lepe_b = (const float*)d_in[7];
  float* out = (float*)d_out;

  char* ws = (char*)d_ws;
  bf16*   Xb    = (bf16*)(ws);
  float*  kvp   = (float*)(ws);                  // aliases Xb (dead after proj)
  bf16*   Wcat  = (bf16*)(ws + 33554432);
  bf16*   Wob   = (bf16*)(ws + 41943040);
  float2* tab   = (float2*)(ws + 44040192);
  float*  ksump = (float*)(ws + 44040192);       // aliases tab (dead after proj)
  float*  vsump = (float*)(ws + 44302336);
  bf16*   QKVG  = (bf16*)(ws + 46137344);
  float*  ksum  = (float*)(ws + 180355072);
  float*  vsum  = (float*)(ws + 180371456);
  bf16*   kvT   = (bf16*)(ws + 180387840);
  bf16*   obuf  = (bf16*)(ws + 181960704);

  prep_kernel<<<22528, 256, 0, stream>>>(X, Wq, Wk, Wv, Wg, Wo, Xb, Wcat, Wob, tab);

  gemm_qkvg<<<1024, 512, 0, stream>>>(Xb, Wcat, QKVG, tab);

  kv_mfma<<<dim3(16, 32), 256, 0, stream>>>(QKVG, kvp, ksump, vsump);
  kv_reduce<<<2048, 256, 0, stream>>>(kvp, ksump, vsump, kvT, ksum, vsum);

  gemm_num<<<dim3(32, 8, 4), 256, 0, stream>>>(QKVG, kvT, ksum, vsum, lepe_w, lepe_b, obuf);

  gemm_final<<<1024, 256, 0, stream>>>(obuf, Wob, out);
}